// Round 5
// baseline (663.803 us; speedup 1.0000x reference)
//
#include <hip/hip_runtime.h>

typedef __attribute__((ext_vector_type(8))) short bf16x8;
typedef __attribute__((ext_vector_type(4))) float f32x4;
typedef __attribute__((ext_vector_type(4))) unsigned short u16x4;

#define BM 256
#define BN 256
#define BK 64

// ---------- exact power of two: 2^e for e in [-127, 127] ----------
__device__ __forceinline__ float pow2i(int e) {
  if (e >= -126) return __uint_as_float((unsigned)(e + 127) << 23);
  return __uint_as_float(0x00400000u >> (-126 - e)); // e == -127 -> 2^-127 subnormal
}

// ---------- emulate RNE cast to e4m3fn (saturating), then dequant ----------
__device__ __forceinline__ float qdq_e4m3(float x, float inv, float scale) {
  float s = x * inv;            // exact: inv is a power of two
  float a = fabsf(s);
  int ee = (int)((__float_as_uint(a) >> 23) & 0xffu) - 127;  // floor(log2(a)) for normals
  ee = ee < -6 ? -6 : (ee > 8 ? 8 : ee);                     // clamp to e4m3 binades
  float istep = __uint_as_float((unsigned)(130 - ee) << 23); // 2^(3-ee)
  float step  = __uint_as_float((unsigned)(124 + ee) << 23); // 2^(ee-3)
  float q = rintf(a * istep) * step;  // RNE, matches jnp.round
  q = fminf(q, 448.0f);               // saturate (e4m3fn has no inf)
  return copysignf(q, s) * scale;     // exact in bf16 (<=4 significant bits * 2^k)
}

__device__ __forceinline__ u16x4 qdq_pack(float4 v) {
  float am = fmaxf(fmaxf(fabsf(v.x), fabsf(v.y)), fmaxf(fabsf(v.z), fabsf(v.w)));
  am = fmaxf(am, __shfl_xor(am, 1));
  am = fmaxf(am, __shfl_xor(am, 2));
  am = fmaxf(am, __shfl_xor(am, 4));
  int e = (int)((__float_as_uint(am) >> 23) & 0xffu) - 135; // floor(log2)-8
  e = e < -127 ? -127 : (e > 127 ? 127 : e);
  float scale = pow2i(e);
  float inv   = pow2i(-e);
  u16x4 o;
  o[0] = (unsigned short)(__float_as_uint(qdq_e4m3(v.x, inv, scale)) >> 16);
  o[1] = (unsigned short)(__float_as_uint(qdq_e4m3(v.y, inv, scale)) >> 16);
  o[2] = (unsigned short)(__float_as_uint(qdq_e4m3(v.z, inv, scale)) >> 16);
  o[3] = (unsigned short)(__float_as_uint(qdq_e4m3(v.w, inv, scale)) >> 16);
  return o;
}

// ---------- fused MX quant+dequant for BOTH tensors in one launch ----------
// 8 consecutive lanes cover one 32-elem block; nx4 % 8 == 0 so groups never straddle.
__global__ void quant_mx2(const float4* __restrict__ x,  u16x4* __restrict__ xq, long long nx4,
                          const float4* __restrict__ wt, u16x4* __restrict__ wq, long long nw4) {
  long long i = (long long)blockIdx.x * blockDim.x + threadIdx.x;
  long long total = nx4 + nw4;
  if (i >= total) return;
  const float4* in = (i < nx4) ? (x + i) : (wt + (i - nx4));
  u16x4* out = (i < nx4) ? (xq + i) : (wq + (i - nx4));
  *out = qdq_pack(*in);
}

// ---------- async global -> LDS, 16B per lane ----------
__device__ __forceinline__ void gload_lds16(const void* g, void* l) {
  __builtin_amdgcn_global_load_lds(
      (const __attribute__((address_space(1))) unsigned int*)g,
      (__attribute__((address_space(3))) unsigned int*)l, 16, 0, 0);
}

#define BAR() do { asm volatile("" ::: "memory"); \
                   __builtin_amdgcn_s_barrier();  \
                   asm volatile("" ::: "memory"); } while (0)
#define WAIT_VM0() asm volatile("s_waitcnt vmcnt(0)" ::: "memory")
#define WAIT_VM4() asm volatile("s_waitcnt vmcnt(4)" ::: "memory")
#define WAIT_VM6() asm volatile("s_waitcnt vmcnt(6)" ::: "memory")

// ---------- 256x256 bf16 MFMA GEMM, 8-phase / 2-K-tiles-per-iter ----------
// C[M,N] = A[M,K]*B[N,K]^T + bias. Even K-tiles in buf0, odd in buf1 (static).
// Per window (phase): exactly 6 ds_read_b128 + {0,2,4,2} global_load_lds.
// Stages land >=4 windows before first read; vmcnt(4)/vmcnt(6) at end of
// W1/W5 and W2/W6 drain exactly the distance-4 half-tiles. Last iter: vmcnt(0).
// T2 st-swizzle: LDS elem = row*64 + (col ^ ((row&7)*8)); inverse-swizzled
// global source (linear gload_lds dest), same XOR on ds_read.
__global__ __launch_bounds__(512, 2) void gemm_mx(
    const unsigned short* __restrict__ A, const unsigned short* __restrict__ B,
    const float* __restrict__ bias, float* __restrict__ C,
    int M, int N, int K) {
  __shared__ __align__(16) unsigned short As[2][BM * BK];   // 64 KB
  __shared__ __align__(16) unsigned short Bs[2][BN * BK];   // 64 KB

  const int tid = threadIdx.x;
  const int l  = tid & 63, w = tid >> 6;
  const int wr = w >> 2, wc = w & 3;          // 2 x 4 wave grid, each wave: 128x64 out
  const int rr = l & 15, kq = l >> 4;

  const int nbx = N / BN;
  const int bid = blockIdx.x;
  const int cpx = gridDim.x >> 3;             // grid % 8 == 0 (512)
  const int swz = (bid & 7) * cpx + (bid >> 3);
  const int by = swz / nbx, bx = swz % nbx;

  const unsigned short* gA = A + (size_t)by * BM * K;
  const unsigned short* gB = B + (size_t)bx * BN * K;

  unsigned short* As0 = As[0]; unsigned short* As1 = As[1];
  unsigned short* Bs0 = Bs[0]; unsigned short* Bs1 = Bs[1];

  f32x4 acc[8][4] = {};

  const int swx   = (rr & 7) * 8;             // element-space XOR for reads
  const int kofs0 = (kq * 8) ^ swx;           // kk=0
  const int kofs1 = (32 + kq * 8) ^ swx;      // kk=1

#define STAGE(G, L, CH, KT) do {                                   \
    int _ch = (CH);                                                \
    int _row = _ch >> 3;                                           \
    int _c16 = (_ch & 7) ^ (_row & 7);                             \
    gload_lds16((G) + (size_t)_row * K + (KT) + _c16 * 8,          \
                (L) + _ch * 8);                                    \
  } while (0)

  // fragments: af0 = A rows wr*128+m*16; af1 = +64. bgA/bgN = B cols wc*64+n*16
  // (cur/next tile); bgB = B cols wc*64+32+n*16.
  bf16x8 af0[4][2], af1[4][2], bgA[2][2], bgB[2][2], bgN[2][2];

#define RD_A8(ARR, MI, HALF, LP) do {                              \
    const int rb = (wr * 128 + (HALF) * 64 + (MI) * 16 + rr) * BK; \
    ARR[MI][0] = *(const bf16x8*)&LP[rb + kofs0];                  \
    ARR[MI][1] = *(const bf16x8*)&LP[rb + kofs1]; } while (0)
#define RD_B8(ARR, NI, HALF, LP) do {                              \
    const int rb = (wc * 64 + (HALF) * 32 + (NI) * 16 + rr) * BK;  \
    ARR[NI][0] = *(const bf16x8*)&LP[rb + kofs0];                  \
    ARR[NI][1] = *(const bf16x8*)&LP[rb + kofs1]; } while (0)

#define MFMAQ(MB, NB, AF, BG)                                      \
  __builtin_amdgcn_s_setprio(1);                                   \
  _Pragma("unroll")                                                \
  for (int kk = 0; kk < 2; ++kk)                                   \
    _Pragma("unroll")                                              \
    for (int m = 0; m < 4; ++m)                                    \
      _Pragma("unroll")                                            \
      for (int n = 0; n < 2; ++n)                                  \
        acc[(MB)*4+m][(NB)+n] = __builtin_amdgcn_mfma_f32_16x16x32_bf16( \
            AF[m][kk], BG[n][kk], acc[(MB)*4+m][(NB)+n], 0, 0, 0); \
  __builtin_amdgcn_s_setprio(0);

  // ---- prologue: stage tiles 0 (buf0) and 1 (buf1), then pre-read P0's frags ----
  STAGE(gA, As0, tid, 0);        STAGE(gA, As0, tid + 512, 0);
  STAGE(gA, As0, tid + 1024, 0); STAGE(gA, As0, tid + 1536, 0);
  STAGE(gB, Bs0, tid, 0);        STAGE(gB, Bs0, tid + 512, 0);
  STAGE(gB, Bs0, tid + 1024, 0); STAGE(gB, Bs0, tid + 1536, 0);
  STAGE(gA, As1, tid, BK);        STAGE(gA, As1, tid + 512, BK);
  STAGE(gA, As1, tid + 1024, BK); STAGE(gA, As1, tid + 1536, BK);
  STAGE(gB, Bs1, tid, BK);        STAGE(gB, Bs1, tid + 512, BK);
  STAGE(gB, Bs1, tid + 1024, BK); STAGE(gB, Bs1, tid + 1536, BK);
  WAIT_VM0();
  BAR();
  RD_A8(af0, 0, 0, As0); RD_A8(af0, 1, 0, As0);
  RD_A8(af0, 2, 0, As0); RD_A8(af0, 3, 0, As0);
  RD_B8(bgA, 0, 0, Bs0); RD_B8(bgA, 1, 0, Bs0);

  const int NTK = K / BK;      // 64
  const int NIT = NTK / 2;     // 32
  for (int it = 0; it < NIT; ++it) {
    const bool last = (it == NIT - 1);
    const int kt2 = (2 * it + 2) * BK, kt3 = (2 * it + 3) * BK;

    // ---- W0: P0 = Q0(tau): af0 x bgA
    RD_B8(bgB, 0, 1, Bs0); RD_B8(bgB, 1, 1, Bs0); RD_A8(af1, 0, 1, As0);
    BAR();
    MFMAQ(0, 0, af0, bgA)
    BAR();

    // ---- W1: P1 = Q1(tau): af0 x bgB; stage B-H1(tau+2)
    RD_A8(af1, 1, 1, As0); RD_A8(af1, 2, 1, As0); RD_A8(af1, 3, 1, As0);
    if (!last) { STAGE(gB, Bs0, tid + 1024, kt2); STAGE(gB, Bs0, tid + 1536, kt2); }
    BAR();
    MFMAQ(0, 2, af0, bgB)
    if (last) { WAIT_VM0(); } else { WAIT_VM4(); }
    BAR();

    // ---- W2: P2 = Q2(tau): af1 x bgB; read af0(tau+1); stage A(tau+2) full
    RD_A8(af0, 0, 0, As1); RD_A8(af0, 1, 0, As1); RD_A8(af0, 2, 0, As1);
    if (!last) { STAGE(gA, As0, tid, kt2);        STAGE(gA, As0, tid + 512, kt2);
                 STAGE(gA, As0, tid + 1024, kt2); STAGE(gA, As0, tid + 1536, kt2); }
    BAR();
    MFMAQ(1, 2, af1, bgB)
    if (last) { WAIT_VM0(); } else { WAIT_VM6(); }
    BAR();

    // ---- W3: P3 = Q3(tau): af1 x bgA; read bgN(tau+1); stage B-H0(tau+2)
    RD_A8(af0, 3, 0, As1); RD_B8(bgN, 0, 0, Bs1); RD_B8(bgN, 1, 0, Bs1);
    if (!last) { STAGE(gB, Bs0, tid, kt2); STAGE(gB, Bs0, tid + 512, kt2); }
    BAR();
    MFMAQ(1, 0, af1, bgA)
    BAR();

    // ---- W4: P4 = Q0(tau+1): af0 x bgN
    RD_B8(bgB, 0, 1, Bs1); RD_B8(bgB, 1, 1, Bs1); RD_A8(af1, 0, 1, As1);
    BAR();
    MFMAQ(0, 0, af0, bgN)
    BAR();

    // ---- W5: P5 = Q1(tau+1): af0 x bgB; stage B-H1(tau+3)
    RD_A8(af1, 1, 1, As1); RD_A8(af1, 2, 1, As1); RD_A8(af1, 3, 1, As1);
    if (!last) { STAGE(gB, Bs1, tid + 1024, kt3); STAGE(gB, Bs1, tid + 1536, kt3); }
    BAR();
    MFMAQ(0, 2, af0, bgB)
    if (last) { WAIT_VM0(); } else { WAIT_VM4(); }
    BAR();

    // ---- W6: P6 = Q2(tau+1): af1 x bgB; read af0(tau+2); stage A(tau+3) full
    RD_A8(af0, 0, 0, As0); RD_A8(af0, 1, 0, As0); RD_A8(af0, 2, 0, As0);
    if (!last) { STAGE(gA, As1, tid, kt3);        STAGE(gA, As1, tid + 512, kt3);
                 STAGE(gA, As1, tid + 1024, kt3); STAGE(gA, As1, tid + 1536, kt3); }
    BAR();
    MFMAQ(1, 2, af1, bgB)
    if (last) { WAIT_VM0(); } else { WAIT_VM6(); }
    BAR();

    // ---- W7: P7 = Q3(tau+1): af1 x bgN; read bgA(tau+2); stage B-H0(tau+3)
    RD_A8(af0, 3, 0, As0); RD_B8(bgA, 0, 0, Bs0); RD_B8(bgA, 1, 0, Bs0);
    if (!last) { STAGE(gB, Bs1, tid, kt3); STAGE(gB, Bs1, tid + 512, kt3); }
    BAR();
    MFMAQ(1, 0, af1, bgN)
    BAR();
  }

  // ---- epilogue: C[row][col] = acc + bias[col]; row=(l>>4)*4+j, col=l&15 ----
#pragma unroll
  for (int ni = 0; ni < 4; ++ni) {
    const int col = bx * BN + wc * 64 + ni * 16 + rr;
    const float bv = bias[col];
#pragma unroll
    for (int mi = 0; mi < 8; ++mi) {
      const int row0 = by * BM + wr * 128 + mi * 16 + kq * 4;
#pragma unroll
      for (int j = 0; j < 4; ++j) {
        C[(size_t)(row0 + j) * N + col] = acc[mi][ni][j] + bv;
      }
    }
  }
}

extern "C" void kernel_launch(void* const* d_in, const int* in_sizes, int n_in,
                              void* d_out, int out_size, void* d_ws, size_t ws_size,
                              hipStream_t stream) {
  const float* x    = (const float*)d_in[0];
  const float* wt   = (const float*)d_in[1];
  const float* bias = (const float*)d_in[2];
  float* out = (float*)d_out;

  const int N = in_sizes[2];                       // 4096
  const int K = (int)((long long)in_sizes[1] / N); // 4096
  const int M = (int)((long long)in_sizes[0] / K); // 8192

  unsigned short* xq = (unsigned short*)d_ws;      // M*K bf16 (64 MB)
  unsigned short* wq = xq + (size_t)M * K;         // N*K bf16 (32 MB)

  long long nx4 = (long long)M * K / 4;
  long long nw4 = (long long)N * K / 4;
  long long tot = nx4 + nw4;
  int gq = (int)((tot + 255) / 256);
  quant_mx2<<<gq, 256, 0, stream>>>((const float4*)x, (u16x4*)xq, nx4,
                                    (const float4*)wt, (u16x4*)wq, nw4);

  dim3 grid((M / BM) * (N / BN));                  // 32*16 = 512, %8==0
  gemm_mx<<<grid, 512, 0, stream>>>(xq, wq, bias, out, M, N, K);
}